// Round 6
// baseline (334.556 us; speedup 1.0000x reference)
//
#include <hip/hip_runtime.h>
#include <stdint.h>

#define FEAT_STRIDE 16
#define PRE_NMS 6000
#define POST_NMS 300
#define NMS_TH 0.7f

static constexpr int B_ = 2, A_ = 9, H_ = 32, W_ = 32, T_ = 16;
static constexpr int LOC = H_ * W_ * T_;   // 16384
static constexpr int N_ = LOC * A_;        // 147456
static constexpr int NBIN = 65536;
static constexpr int CAP = 8192;           // candidate capacity per batch
static constexpr int NW = 94;              // ceil(6000/64) mask words per row
static constexpr int ROWS = 6016;          // NW*64 padded rows

// sortedBox row layout (8 floats, 32B aligned): [x1,y1,z1,x2, y2,z2,vol,score]

// ---- float <-> monotonic u32 key ----
__device__ __forceinline__ uint32_t f2u(float f) {
    uint32_t b = __float_as_uint(f);
    return b ^ ((b >> 31) ? 0xFFFFFFFFu : 0x80000000u);
}
__device__ __forceinline__ float u2f(uint32_t u) {
    uint32_t b = (u >> 31) ? (u ^ 0x80000000u) : ~u;
    return __uint_as_float(b);
}

// 1) histogram of score keys' top-16 bits (coalesced: loc innermost)
__global__ void hist_kernel(const float* __restrict__ scores_map,
                            unsigned int* __restrict__ hist) {
    int gid = blockIdx.x * blockDim.x + threadIdx.x;
    if (gid >= B_ * N_) return;
    int b = gid / N_;
    int r = gid - b * N_;
    int a = r / LOC;
    int loc = r - a * LOC;
    float sc = scores_map[((size_t)(b * 2 * A_ + A_ + a)) * LOC + loc];
    uint32_t u = f2u(sc);
    atomicAdd(&hist[b * NBIN + (u >> 16)], 1u);
}

// 2) per batch: find threshold bin (cumulative-from-top crosses PRE_NMS) AND
//    convert hist in place to per-bin bucket-start offsets (suffix-sum of counts
//    above), writing an immutable copy to binbase.
__global__ void scan_kernel(unsigned int* __restrict__ hist,
                            unsigned int* __restrict__ binbase,
                            unsigned int* __restrict__ thr) {
    int bb = blockIdx.x;
    int t = threadIdx.x;                 // 1024 threads
    __shared__ unsigned int ssum[1024];
    unsigned int* h = hist + (size_t)bb * NBIN;
    unsigned int* bs = binbase + (size_t)bb * NBIN;
    int base = t * 64;
    const uint4* h4 = reinterpret_cast<const uint4*>(h + base);
    unsigned int s = 0;
#pragma unroll
    for (int q = 0; q < 16; ++q) {
        uint4 v = h4[q];
        s += v.x + v.y + v.z + v.w;
    }
    ssum[t] = s;
    __syncthreads();
    for (int off = 1; off < 1024; off <<= 1) {
        unsigned int v = (t + off < 1024) ? ssum[t + off] : 0u;
        __syncthreads();
        ssum[t] += v;
        __syncthreads();
    }
    unsigned int excl = (t < 1023) ? ssum[t + 1] : 0u;   // keys in groups above
    bool crossing = (excl < (unsigned)PRE_NMS && excl + s >= (unsigned)PRE_NMS);
    // walk own 64 bins top-down: offset rewrite + threshold detection
    unsigned int run = excl;
    for (int q = 63; q >= 0; --q) {
        unsigned int c = h[base + q];
        unsigned int off = run;          // # keys in strictly higher bins
        run += c;
        h[base + q] = off;
        bs[base + q] = off;
        if (crossing && run >= (unsigned)PRE_NMS) {
            thr[bb * 2 + 0] = (unsigned)(base + q);
            thr[bb * 2 + 1] = run;       // total candidates scattered
            crossing = false;
        }
    }
}

// 3) compact: scatter passing keys into their bin's bucket.
//    hist[bin] holds the bucket cursor (init = bucket start); atomicAdd returns slot.
__global__ void __launch_bounds__(256) compact_kernel(
        const float* __restrict__ scores_map,
        const unsigned int* __restrict__ thr,
        unsigned long long* __restrict__ cand,
        unsigned int* __restrict__ hist) {
    int tid = threadIdx.x;
    int gid = blockIdx.x * 256 + tid;        // grid sized exactly: no OOB
    int b = gid / N_;
    int r = gid - b * N_;
    int a = r / LOC;
    int loc = r - a * LOC;
    float sc = scores_map[((size_t)(b * 2 * A_ + A_ + a)) * LOC + loc];
    uint32_t u = f2u(sc);
    uint32_t bin = u >> 16;
    if (bin >= thr[b * 2]) {
        int n = loc * A_ + a;   // reference flat index
        unsigned long long key = ((unsigned long long)u << 18)
                               | (unsigned long long)(N_ - 1 - n);
        unsigned int slot = atomicAdd(&hist[b * NBIN + bin], 1u);
        if (slot < (unsigned)CAP)
            cand[(size_t)b * CAP + slot] = key;
    }
}

// 4) bucket rank + decode: rank = binbase[bin] + (# same-bucket keys greater).
//    Buckets are tiny (avg ~5) and L2-resident. Decodes into sortedBox[rank].
__global__ void __launch_bounds__(256) bucket_decode(
        const unsigned long long* __restrict__ cand,
        const unsigned int* __restrict__ hist,     // bucket ends after compact
        const unsigned int* __restrict__ binbase,  // bucket starts
        const unsigned int* __restrict__ thr,
        const float* __restrict__ bbox_frame,
        const float* __restrict__ im_info,
        const float* __restrict__ anchors,
        float* __restrict__ sortedBox) {
    int gid = blockIdx.x * 256 + threadIdx.x;
    int bb = gid / CAP;
    int i = gid - bb * CAP;
    int count = (int)thr[bb * 2 + 1];
    if (count > CAP) count = CAP;
    if (i >= count) return;
    const unsigned long long* cb = cand + (size_t)bb * CAP;
    unsigned long long me = cb[i];
    int bin = (int)(me >> 34);
    int start = (int)binbase[bb * NBIN + bin];
    int end = (int)hist[bb * NBIN + bin];
    if (end > count) end = count;
    int rank = start;
    for (int q = start; q < end; ++q)
        rank += (cb[q] > me);
    if (rank >= PRE_NMS) return;

    uint32_t u = (uint32_t)(me >> 18);
    int n = N_ - 1 - (int)(me & 0x3FFFFull);
    int a = n % A_;
    int loc = n / A_;
    int k = loc % T_;
    int j = (loc / T_) % W_;
    int ii = loc / (T_ * W_);

    float ax1 = anchors[a * 6 + 0] + (float)(FEAT_STRIDE * j);
    float ay1 = anchors[a * 6 + 1] + (float)(FEAT_STRIDE * ii);
    float az1 = anchors[a * 6 + 2] + (float)k;
    float ax2 = anchors[a * 6 + 3] + (float)(FEAT_STRIDE * j);
    float ay2 = anchors[a * 6 + 4] + (float)(FEAT_STRIDE * ii);
    float az2 = anchors[a * 6 + 5] + (float)k;
    float aw = ax2 - ax1 + 1.0f, ah = ay2 - ay1 + 1.0f, al = az2 - az1 + 1.0f;
    float acx = ax1 + 0.5f * aw, acy = ay1 + 0.5f * ah, acz = az1 + 0.5f * al;

    const float* dp = bbox_frame + ((size_t)(bb * 6 * A_ + a * 6)) * LOC
                    + ii * (W_ * T_) + j * T_ + k;
    float d0 = dp[0 * LOC], d1 = dp[1 * LOC], d2 = dp[2 * LOC];
    float d3 = dp[3 * LOC], d4 = dp[4 * LOC], d5 = dp[5 * LOC];

    float pcx = d0 * aw + acx, pcy = d1 * ah + acy, pcz = d2 * al + acz;
    float pw = expf(d3) * aw, ph = expf(d4) * ah, pl = expf(d5) * al;

    float x1 = pcx - 0.5f * pw, y1 = pcy - 0.5f * ph, z1 = pcz - 0.5f * pl;
    float x2 = pcx + 0.5f * pw, y2 = pcy + 0.5f * ph, z2 = pcz + 0.5f * pl;

    float lx = im_info[1] - 1.0f, ly = im_info[0] - 1.0f, lz = im_info[2] - 1.0f;
    x1 = fminf(fmaxf(x1, 0.0f), lx); y1 = fminf(fmaxf(y1, 0.0f), ly); z1 = fminf(fmaxf(z1, 0.0f), lz);
    x2 = fminf(fmaxf(x2, 0.0f), lx); y2 = fminf(fmaxf(y2, 0.0f), ly); z2 = fminf(fmaxf(z2, 0.0f), lz);

    float vol = (x2 - x1 + 1.0f) * (y2 - y1 + 1.0f) * (z2 - z1 + 1.0f);
    float* p = sortedBox + ((size_t)bb * ROWS + rank) * 8;
    p[0] = x1; p[1] = y1; p[2] = z1; p[3] = x2;
    p[4] = y2; p[5] = z2; p[6] = vol; p[7] = u2f(u);
}

// 5) IoU bitmask: mask[bb][i][w] bit b = (j=64w+b > i) && IoU(i,j) > TH
__global__ void mask_build(const float* __restrict__ sortedBox,
                           unsigned long long* __restrict__ mask,
                           unsigned long long* __restrict__ diagArr) {
    int g = blockIdx.x / NW, w = blockIdx.x % NW;
    if (w < g) return;                      // only need upper triangle words
    int bb = blockIdx.y;
    int lane = threadIdx.x;                 // 64 threads
    __shared__ float colb[64][7];           // x1,y1,z1,x2,y2,z2,vol
    const float* sb = sortedBox + (size_t)bb * ROWS * 8;
    int col = w * 64 + lane;
    if (col < PRE_NMS) {
        const float4* cp4 = reinterpret_cast<const float4*>(sb + (size_t)col * 8);
        float4 lo = cp4[0], hi = cp4[1];
        colb[lane][0] = lo.x; colb[lane][1] = lo.y; colb[lane][2] = lo.z;
        colb[lane][3] = lo.w; colb[lane][4] = hi.x; colb[lane][5] = hi.y;
        colb[lane][6] = hi.z;
    } else {
        colb[lane][0] = 3e8f; colb[lane][1] = 0.f; colb[lane][2] = 0.f;
        colb[lane][3] = -3e8f; colb[lane][4] = 0.f; colb[lane][5] = 0.f;
        colb[lane][6] = 1.0f;
    }
    __syncthreads();
    int row = g * 64 + lane;
    if (row >= PRE_NMS) return;
    const float4* rp4 = reinterpret_cast<const float4*>(sb + (size_t)row * 8);
    float4 rlo = rp4[0], rhi = rp4[1];
    float x1 = rlo.x, y1 = rlo.y, z1 = rlo.z;
    float x2 = rlo.w, y2 = rhi.x, z2 = rhi.y, v = rhi.z;
    unsigned long long word = 0;
    for (int b2 = 0; b2 < 64; ++b2) {
        float iw = fminf(x2, colb[b2][3]) - fmaxf(x1, colb[b2][0]) + 1.0f;
        float ih = fminf(y2, colb[b2][4]) - fmaxf(y1, colb[b2][1]) + 1.0f;
        float il = fminf(z2, colb[b2][5]) - fmaxf(z1, colb[b2][2]) + 1.0f;
        iw = fmaxf(iw, 0.0f); ih = fmaxf(ih, 0.0f); il = fmaxf(il, 0.0f);
        float inter = iw * ih * il;
        float iou = inter / (v + colb[b2][6] - inter);
        int cidx = w * 64 + b2;
        if (cidx > row && iou > NMS_TH) word |= (1ull << b2);
    }
    mask[((size_t)bb * ROWS + row) * NW + w] = word;
    if (w == g) diagArr[(size_t)bb * ROWS + row] = word;
}

// 6) greedy suppress: wave0 scans survivors; 16 waves parallelize row ORs.
__global__ void __launch_bounds__(1024) suppress_kernel(
        const unsigned long long* __restrict__ mask,
        const unsigned long long* __restrict__ diagArr,
        const float* __restrict__ sortedBox,
        float* __restrict__ out) {
    int bb = blockIdx.x;
    int tid = threadIdx.x;
    int lane = tid & 63, wave = tid >> 6;
    __shared__ unsigned long long remv[NW];
    __shared__ int keptRows[64];
    __shared__ int s_nk;
    for (int i = tid; i < NW; i += 1024) remv[i] = 0ull;
    if (tid == 0) remv[NW - 1] = ~((1ull << (PRE_NMS - (NW - 1) * 64)) - 1ull);
    __syncthreads();

    const unsigned long long* M = mask + (size_t)bb * ROWS * NW;
    const unsigned long long* D = diagArr + (size_t)bb * ROWS;
    const float* sb = sortedBox + (size_t)bb * ROWS * 8;
    float* ob = out + (size_t)bb * POST_NMS * 7;

    int kept_total = 0;
    for (int c = 0; c < NW; ++c) {
        if (wave == 0) {
            unsigned long long diag = D[c * 64 + lane];        // coalesced 512B
            unsigned long long alive = ~remv[c];
            int nk = 0;
            while (alive && (kept_total + nk) < POST_NMS) {
                int b = __builtin_ctzll(alive);
                if (lane == 0) keptRows[nk] = c * 64 + b;
                ++nk;
                unsigned long long d = __shfl(diag, b);
                alive &= ~(d | (1ull << b));
            }
            if (lane == 0) s_nk = nk;
        }
        __syncthreads();
        int nk = s_nk;
        for (int w2 = c + 1 + tid; w2 < NW; w2 += 1024) {
            unsigned long long v = remv[w2];
            for (int i = 0; i < nk; ++i)
                v |= M[(size_t)keptRows[i] * NW + w2];
            remv[w2] = v;
        }
        // output rows: [score, x1,y1,z1,x2,y2,z2]; sb row: [x1..z2, vol, score]
        for (int e = tid; e < nk * 7; e += 1024) {
            int i = e / 7, j = e - i * 7;
            ob[(size_t)(kept_total + i) * 7 + j] =
                sb[(size_t)keptRows[i] * 8 + (j == 0 ? 7 : j - 1)];
        }
        kept_total += nk;
        __syncthreads();
        if (kept_total >= POST_NMS) break;
    }
    for (int idx = kept_total * 7 + tid; idx < POST_NMS * 7; idx += 1024)
        ob[idx] = 0.0f;
}

extern "C" void kernel_launch(void* const* d_in, const int* in_sizes, int n_in,
                              void* d_out, int out_size, void* d_ws, size_t ws_size,
                              hipStream_t stream) {
    const float* scores_map = (const float*)d_in[0];
    const float* bbox_frame = (const float*)d_in[1];
    const float* im_info    = (const float*)d_in[2];
    const float* anchors    = (const float*)d_in[3];
    float* out = (float*)d_out;

    // workspace layout (bytes) — total 10,088,464 (≤ proven 10,088,472)
    char* ws = (char*)d_ws;
    unsigned long long* mask    = (unsigned long long*)(ws + 0);          // 9,048,064
    unsigned int* binbase       = (unsigned int*)(ws + 0);                // aliases mask
                                                                          // (dead before mask_build) 524,288
    float* sortedBox            = (float*)(ws + 9048064);                 // 385,024
    unsigned long long* cand    = (unsigned long long*)(ws + 9433088);    // 131,072
    unsigned int* hist          = (unsigned int*)(ws + 9564160);          // 524,288
    unsigned long long* diagArr = (unsigned long long*)(ws + 9564160);    // aliases hist
                                                                          // (hist dead after decode) 96,256
    unsigned int* thr           = (unsigned int*)(ws + 10088448);         // 16

    hipMemsetAsync(hist, 0, 524288, stream);

    int total = B_ * N_;
    hist_kernel<<<(total + 255) / 256, 256, 0, stream>>>(scores_map, hist);
    scan_kernel<<<B_, 1024, 0, stream>>>(hist, binbase, thr);
    compact_kernel<<<total / 256, 256, 0, stream>>>(scores_map, thr, cand, hist);
    bucket_decode<<<B_ * CAP / 256, 256, 0, stream>>>(cand, hist, binbase, thr,
                                                      bbox_frame, im_info, anchors,
                                                      sortedBox);
    mask_build<<<dim3(NW * NW, B_), 64, 0, stream>>>(sortedBox, mask, diagArr);
    suppress_kernel<<<B_, 1024, 0, stream>>>(mask, diagArr, sortedBox, out);
}

// Round 7
// 213.473 us; speedup vs baseline: 1.5672x; 1.5672x over previous
//
#include <hip/hip_runtime.h>
#include <stdint.h>

#define FEAT_STRIDE 16
#define PRE_NMS 6000
#define POST_NMS 300
#define NMS_TH 0.7f

static constexpr int B_ = 2, A_ = 9, H_ = 32, W_ = 32, T_ = 16;
static constexpr int LOC = H_ * W_ * T_;   // 16384
static constexpr int N_ = LOC * A_;        // 147456
static constexpr int NBIN = 65536;
static constexpr int CAP = 8192;           // candidate capacity per batch
static constexpr int NW = 94;              // ceil(6000/64) mask words per row
static constexpr int ROWS = 6016;          // NW*64 padded rows

// sortedBox row layout (8 floats, 32B aligned): [x1,y1,z1,x2, y2,z2,vol,score]

// ---- float <-> monotonic u32 key ----
__device__ __forceinline__ uint32_t f2u(float f) {
    uint32_t b = __float_as_uint(f);
    return b ^ ((b >> 31) ? 0xFFFFFFFFu : 0x80000000u);
}
__device__ __forceinline__ float u2f(uint32_t u) {
    uint32_t b = (u >> 31) ? (u ^ 0x80000000u) : ~u;
    return __uint_as_float(b);
}

// 1) histogram of score keys' top-16 bits (coalesced: loc innermost)
__global__ void hist_kernel(const float* __restrict__ scores_map,
                            unsigned int* __restrict__ hist) {
    int gid = blockIdx.x * blockDim.x + threadIdx.x;
    if (gid >= B_ * N_) return;
    int b = gid / N_;
    int r = gid - b * N_;
    int a = r / LOC;
    int loc = r - a * LOC;
    float sc = scores_map[((size_t)(b * 2 * A_ + A_ + a)) * LOC + loc];
    uint32_t u = f2u(sc);
    atomicAdd(&hist[b * NBIN + (u >> 16)], 1u);
}

// 2a) per (batch, 1024-bin chunk): block-reduce chunk count (coalesced uint4)
__global__ void __launch_bounds__(256) partial_kernel(
        const unsigned int* __restrict__ hist,
        unsigned int* __restrict__ partials) {
    int c = blockIdx.x, bb = blockIdx.y, t = threadIdx.x;
    const uint4* h4 = reinterpret_cast<const uint4*>(hist + (size_t)bb * NBIN + c * 1024);
    uint4 v = h4[t];
    __shared__ unsigned int red[256];
    red[t] = v.x + v.y + v.z + v.w;
    __syncthreads();
    for (int off = 128; off > 0; off >>= 1) {
        if (t < off) red[t] += red[t + off];
        __syncthreads();
    }
    if (t == 0) partials[bb * 64 + c] = red[0];
}

// 2b) per (batch, chunk): rewrite hist to per-bin suffix offsets (bucket starts),
//     copy to binbase, and detect the PRE_NMS threshold crossing bin.
__global__ void __launch_bounds__(256) rewrite_kernel(
        unsigned int* __restrict__ hist,
        unsigned int* __restrict__ binbase,
        const unsigned int* __restrict__ partials,
        unsigned int* __restrict__ thr) {
    int c = blockIdx.x, bb = blockIdx.y, t = threadIdx.x;
    __shared__ unsigned int sp[64];
    __shared__ unsigned int ssum[256];
    if (t < 64) sp[t] = partials[bb * 64 + t];
    unsigned int* h = hist + (size_t)bb * NBIN + c * 1024;
    unsigned int* bs = binbase + (size_t)bb * NBIN + c * 1024;
    uint4 v = reinterpret_cast<const uint4*>(h)[t];
    ssum[t] = v.x + v.y + v.z + v.w;
    __syncthreads();
    unsigned int chunkBase = 0;
    for (int q = c + 1; q < 64; ++q) chunkBase += sp[q];   // uniform broadcast reads
    // inclusive suffix scan (from high thread index down) over 256 thread sums
    for (int off = 1; off < 256; off <<= 1) {
        unsigned int val = (t + off < 256) ? ssum[t + off] : 0u;
        __syncthreads();
        ssum[t] += val;
        __syncthreads();
    }
    unsigned int run = chunkBase + ((t < 255) ? ssum[t + 1] : 0u); // keys strictly above
    unsigned int cnt[4] = {v.x, v.y, v.z, v.w};
    unsigned int offv[4];
    for (int q = 3; q >= 0; --q) {
        offv[q] = run;
        unsigned int newrun = run + cnt[q];
        if (run < (unsigned)PRE_NMS && newrun >= (unsigned)PRE_NMS) {
            thr[bb * 2 + 0] = (unsigned)(c * 1024 + t * 4 + q);
            thr[bb * 2 + 1] = newrun;    // total candidates scattered
        }
        run = newrun;
    }
    uint4 o4 = {offv[0], offv[1], offv[2], offv[3]};
    reinterpret_cast<uint4*>(h)[t] = o4;    // bucket cursors
    reinterpret_cast<uint4*>(bs)[t] = o4;   // immutable bucket starts
}

// 3) compact: scatter passing keys into their bin's bucket.
//    hist[bin] holds the bucket cursor (init = bucket start); atomicAdd returns slot.
__global__ void __launch_bounds__(256) compact_kernel(
        const float* __restrict__ scores_map,
        const unsigned int* __restrict__ thr,
        unsigned long long* __restrict__ cand,
        unsigned int* __restrict__ hist) {
    int tid = threadIdx.x;
    int gid = blockIdx.x * 256 + tid;        // grid sized exactly: no OOB
    int b = gid / N_;
    int r = gid - b * N_;
    int a = r / LOC;
    int loc = r - a * LOC;
    float sc = scores_map[((size_t)(b * 2 * A_ + A_ + a)) * LOC + loc];
    uint32_t u = f2u(sc);
    uint32_t bin = u >> 16;
    if (bin >= thr[b * 2]) {
        int n = loc * A_ + a;   // reference flat index
        unsigned long long key = ((unsigned long long)u << 18)
                               | (unsigned long long)(N_ - 1 - n);
        unsigned int slot = atomicAdd(&hist[b * NBIN + bin], 1u);
        if (slot < (unsigned)CAP)
            cand[(size_t)b * CAP + slot] = key;
    }
}

// 4) bucket rank + decode: rank = binbase[bin] + (# same-bucket keys greater).
//    Buckets are tiny (avg ~5) and L2-resident. Decodes into sortedBox[rank].
__global__ void __launch_bounds__(256) bucket_decode(
        const unsigned long long* __restrict__ cand,
        const unsigned int* __restrict__ hist,     // bucket ends after compact
        const unsigned int* __restrict__ binbase,  // bucket starts
        const unsigned int* __restrict__ thr,
        const float* __restrict__ bbox_frame,
        const float* __restrict__ im_info,
        const float* __restrict__ anchors,
        float* __restrict__ sortedBox) {
    int gid = blockIdx.x * 256 + threadIdx.x;
    int bb = gid / CAP;
    int i = gid - bb * CAP;
    int count = (int)thr[bb * 2 + 1];
    if (count > CAP) count = CAP;
    if (i >= count) return;
    const unsigned long long* cb = cand + (size_t)bb * CAP;
    unsigned long long me = cb[i];
    int bin = (int)(me >> 34);
    int start = (int)binbase[bb * NBIN + bin];
    int end = (int)hist[bb * NBIN + bin];
    if (end > count) end = count;
    int rank = start;
    for (int q = start; q < end; ++q)
        rank += (cb[q] > me);
    if (rank >= PRE_NMS) return;

    uint32_t u = (uint32_t)(me >> 18);
    int n = N_ - 1 - (int)(me & 0x3FFFFull);
    int a = n % A_;
    int loc = n / A_;
    int k = loc % T_;
    int j = (loc / T_) % W_;
    int ii = loc / (T_ * W_);

    float ax1 = anchors[a * 6 + 0] + (float)(FEAT_STRIDE * j);
    float ay1 = anchors[a * 6 + 1] + (float)(FEAT_STRIDE * ii);
    float az1 = anchors[a * 6 + 2] + (float)k;
    float ax2 = anchors[a * 6 + 3] + (float)(FEAT_STRIDE * j);
    float ay2 = anchors[a * 6 + 4] + (float)(FEAT_STRIDE * ii);
    float az2 = anchors[a * 6 + 5] + (float)k;
    float aw = ax2 - ax1 + 1.0f, ah = ay2 - ay1 + 1.0f, al = az2 - az1 + 1.0f;
    float acx = ax1 + 0.5f * aw, acy = ay1 + 0.5f * ah, acz = az1 + 0.5f * al;

    const float* dp = bbox_frame + ((size_t)(bb * 6 * A_ + a * 6)) * LOC
                    + ii * (W_ * T_) + j * T_ + k;
    float d0 = dp[0 * LOC], d1 = dp[1 * LOC], d2 = dp[2 * LOC];
    float d3 = dp[3 * LOC], d4 = dp[4 * LOC], d5 = dp[5 * LOC];

    float pcx = d0 * aw + acx, pcy = d1 * ah + acy, pcz = d2 * al + acz;
    float pw = expf(d3) * aw, ph = expf(d4) * ah, pl = expf(d5) * al;

    float x1 = pcx - 0.5f * pw, y1 = pcy - 0.5f * ph, z1 = pcz - 0.5f * pl;
    float x2 = pcx + 0.5f * pw, y2 = pcy + 0.5f * ph, z2 = pcz + 0.5f * pl;

    float lx = im_info[1] - 1.0f, ly = im_info[0] - 1.0f, lz = im_info[2] - 1.0f;
    x1 = fminf(fmaxf(x1, 0.0f), lx); y1 = fminf(fmaxf(y1, 0.0f), ly); z1 = fminf(fmaxf(z1, 0.0f), lz);
    x2 = fminf(fmaxf(x2, 0.0f), lx); y2 = fminf(fmaxf(y2, 0.0f), ly); z2 = fminf(fmaxf(z2, 0.0f), lz);

    float vol = (x2 - x1 + 1.0f) * (y2 - y1 + 1.0f) * (z2 - z1 + 1.0f);
    float* p = sortedBox + ((size_t)bb * ROWS + rank) * 8;
    p[0] = x1; p[1] = y1; p[2] = z1; p[3] = x2;
    p[4] = y2; p[5] = z2; p[6] = vol; p[7] = u2f(u);
}

// 5) IoU bitmask: mask[bb][i][w] bit b = (j=64w+b > i) && IoU(i,j) > TH
__global__ void mask_build(const float* __restrict__ sortedBox,
                           unsigned long long* __restrict__ mask,
                           unsigned long long* __restrict__ diagArr) {
    int g = blockIdx.x / NW, w = blockIdx.x % NW;
    if (w < g) return;                      // only need upper triangle words
    int bb = blockIdx.y;
    int lane = threadIdx.x;                 // 64 threads
    __shared__ float colb[64][7];           // x1,y1,z1,x2,y2,z2,vol
    const float* sb = sortedBox + (size_t)bb * ROWS * 8;
    int col = w * 64 + lane;
    if (col < PRE_NMS) {
        const float4* cp4 = reinterpret_cast<const float4*>(sb + (size_t)col * 8);
        float4 lo = cp4[0], hi = cp4[1];
        colb[lane][0] = lo.x; colb[lane][1] = lo.y; colb[lane][2] = lo.z;
        colb[lane][3] = lo.w; colb[lane][4] = hi.x; colb[lane][5] = hi.y;
        colb[lane][6] = hi.z;
    } else {
        colb[lane][0] = 3e8f; colb[lane][1] = 0.f; colb[lane][2] = 0.f;
        colb[lane][3] = -3e8f; colb[lane][4] = 0.f; colb[lane][5] = 0.f;
        colb[lane][6] = 1.0f;
    }
    __syncthreads();
    int row = g * 64 + lane;
    if (row >= PRE_NMS) return;
    const float4* rp4 = reinterpret_cast<const float4*>(sb + (size_t)row * 8);
    float4 rlo = rp4[0], rhi = rp4[1];
    float x1 = rlo.x, y1 = rlo.y, z1 = rlo.z;
    float x2 = rlo.w, y2 = rhi.x, z2 = rhi.y, v = rhi.z;
    unsigned long long word = 0;
    for (int b2 = 0; b2 < 64; ++b2) {
        float iw = fminf(x2, colb[b2][3]) - fmaxf(x1, colb[b2][0]) + 1.0f;
        float ih = fminf(y2, colb[b2][4]) - fmaxf(y1, colb[b2][1]) + 1.0f;
        float il = fminf(z2, colb[b2][5]) - fmaxf(z1, colb[b2][2]) + 1.0f;
        iw = fmaxf(iw, 0.0f); ih = fmaxf(ih, 0.0f); il = fmaxf(il, 0.0f);
        float inter = iw * ih * il;
        float iou = inter / (v + colb[b2][6] - inter);
        int cidx = w * 64 + b2;
        if (cidx > row && iou > NMS_TH) word |= (1ull << b2);
    }
    mask[((size_t)bb * ROWS + row) * NW + w] = word;
    if (w == g) diagArr[(size_t)bb * ROWS + row] = word;
}

// 6) greedy suppress: wave0 scans survivors; 16 waves parallelize row ORs.
__global__ void __launch_bounds__(1024) suppress_kernel(
        const unsigned long long* __restrict__ mask,
        const unsigned long long* __restrict__ diagArr,
        const float* __restrict__ sortedBox,
        float* __restrict__ out) {
    int bb = blockIdx.x;
    int tid = threadIdx.x;
    int lane = tid & 63, wave = tid >> 6;
    __shared__ unsigned long long remv[NW];
    __shared__ int keptRows[64];
    __shared__ int s_nk;
    for (int i = tid; i < NW; i += 1024) remv[i] = 0ull;
    if (tid == 0) remv[NW - 1] = ~((1ull << (PRE_NMS - (NW - 1) * 64)) - 1ull);
    __syncthreads();

    const unsigned long long* M = mask + (size_t)bb * ROWS * NW;
    const unsigned long long* D = diagArr + (size_t)bb * ROWS;
    const float* sb = sortedBox + (size_t)bb * ROWS * 8;
    float* ob = out + (size_t)bb * POST_NMS * 7;

    int kept_total = 0;
    for (int c = 0; c < NW; ++c) {
        if (wave == 0) {
            unsigned long long diag = D[c * 64 + lane];        // coalesced 512B
            unsigned long long alive = ~remv[c];
            int nk = 0;
            while (alive && (kept_total + nk) < POST_NMS) {
                int b = __builtin_ctzll(alive);
                if (lane == 0) keptRows[nk] = c * 64 + b;
                ++nk;
                unsigned long long d = __shfl(diag, b);
                alive &= ~(d | (1ull << b));
            }
            if (lane == 0) s_nk = nk;
        }
        __syncthreads();
        int nk = s_nk;
        for (int w2 = c + 1 + tid; w2 < NW; w2 += 1024) {
            unsigned long long v = remv[w2];
            for (int i = 0; i < nk; ++i)
                v |= M[(size_t)keptRows[i] * NW + w2];
            remv[w2] = v;
        }
        // output rows: [score, x1,y1,z1,x2,y2,z2]; sb row: [x1..z2, vol, score]
        for (int e = tid; e < nk * 7; e += 1024) {
            int i = e / 7, j = e - i * 7;
            ob[(size_t)(kept_total + i) * 7 + j] =
                sb[(size_t)keptRows[i] * 8 + (j == 0 ? 7 : j - 1)];
        }
        kept_total += nk;
        __syncthreads();
        if (kept_total >= POST_NMS) break;
    }
    for (int idx = kept_total * 7 + tid; idx < POST_NMS * 7; idx += 1024)
        ob[idx] = 0.0f;
}

extern "C" void kernel_launch(void* const* d_in, const int* in_sizes, int n_in,
                              void* d_out, int out_size, void* d_ws, size_t ws_size,
                              hipStream_t stream) {
    const float* scores_map = (const float*)d_in[0];
    const float* bbox_frame = (const float*)d_in[1];
    const float* im_info    = (const float*)d_in[2];
    const float* anchors    = (const float*)d_in[3];
    float* out = (float*)d_out;

    // workspace layout (bytes) — total 10,088,976 (≤ proven 10,092,568)
    char* ws = (char*)d_ws;
    unsigned long long* mask    = (unsigned long long*)(ws + 0);          // 9,048,064
    unsigned int* binbase       = (unsigned int*)(ws + 0);                // aliases mask
                                                                          // (dead before mask_build) 524,288
    float* sortedBox            = (float*)(ws + 9048064);                 // 385,024
    unsigned long long* cand    = (unsigned long long*)(ws + 9433088);    // 131,072
    unsigned int* hist          = (unsigned int*)(ws + 9564160);          // 524,288
    unsigned long long* diagArr = (unsigned long long*)(ws + 9564160);    // aliases hist
                                                                          // (hist dead after decode) 96,256
    unsigned int* thr           = (unsigned int*)(ws + 10088448);         // 16
    unsigned int* partials      = (unsigned int*)(ws + 10088464);         // 512

    hipMemsetAsync(hist, 0, 524288, stream);

    int total = B_ * N_;
    hist_kernel<<<(total + 255) / 256, 256, 0, stream>>>(scores_map, hist);
    partial_kernel<<<dim3(64, B_), 256, 0, stream>>>(hist, partials);
    rewrite_kernel<<<dim3(64, B_), 256, 0, stream>>>(hist, binbase, partials, thr);
    compact_kernel<<<total / 256, 256, 0, stream>>>(scores_map, thr, cand, hist);
    bucket_decode<<<B_ * CAP / 256, 256, 0, stream>>>(cand, hist, binbase, thr,
                                                      bbox_frame, im_info, anchors,
                                                      sortedBox);
    mask_build<<<dim3(NW * NW, B_), 64, 0, stream>>>(sortedBox, mask, diagArr);
    suppress_kernel<<<B_, 1024, 0, stream>>>(mask, diagArr, sortedBox, out);
}

// Round 8
// 186.440 us; speedup vs baseline: 1.7944x; 1.1450x over previous
//
#include <hip/hip_runtime.h>
#include <stdint.h>

#define FEAT_STRIDE 16
#define PRE_NMS 6000
#define POST_NMS 300
#define NMS_TH 0.7f

static constexpr int B_ = 2, A_ = 9, H_ = 32, W_ = 32, T_ = 16;
static constexpr int LOC = H_ * W_ * T_;   // 16384
static constexpr int N_ = LOC * A_;        // 147456
static constexpr int NBIN = 65536;
static constexpr int CAP = 8192;           // candidate capacity per batch
static constexpr int NW = 94;              // ceil(6000/64) mask words per row
static constexpr int ROWS = 6016;          // NW*64 padded rows

// sortedBox row layout (8 floats, 32B aligned): [x1,y1,z1,x2, y2,z2,vol,score]

// ---- float <-> monotonic u32 key ----
__device__ __forceinline__ uint32_t f2u(float f) {
    uint32_t b = __float_as_uint(f);
    return b ^ ((b >> 31) ? 0xFFFFFFFFu : 0x80000000u);
}
__device__ __forceinline__ float u2f(uint32_t u) {
    uint32_t b = (u >> 31) ? (u ^ 0x80000000u) : ~u;
    return __uint_as_float(b);
}

// 1) histogram of score keys' top-16 bits (coalesced: loc innermost)
__global__ void hist_kernel(const float* __restrict__ scores_map,
                            unsigned int* __restrict__ hist) {
    int gid = blockIdx.x * blockDim.x + threadIdx.x;
    if (gid >= B_ * N_) return;
    int b = gid / N_;
    int r = gid - b * N_;
    int a = r / LOC;
    int loc = r - a * LOC;
    float sc = scores_map[((size_t)(b * 2 * A_ + A_ + a)) * LOC + loc];
    uint32_t u = f2u(sc);
    atomicAdd(&hist[b * NBIN + (u >> 16)], 1u);
}

// 2a) per (batch, 1024-bin chunk): block-reduce chunk count (coalesced uint4)
__global__ void __launch_bounds__(256) partial_kernel(
        const unsigned int* __restrict__ hist,
        unsigned int* __restrict__ partials) {
    int c = blockIdx.x, bb = blockIdx.y, t = threadIdx.x;
    const uint4* h4 = reinterpret_cast<const uint4*>(hist + (size_t)bb * NBIN + c * 1024);
    uint4 v = h4[t];
    __shared__ unsigned int red[256];
    red[t] = v.x + v.y + v.z + v.w;
    __syncthreads();
    for (int off = 128; off > 0; off >>= 1) {
        if (t < off) red[t] += red[t + off];
        __syncthreads();
    }
    if (t == 0) partials[bb * 64 + c] = red[0];
}

// 2b) per (batch, chunk): rewrite hist to per-bin suffix offsets (bucket starts),
//     copy to binbase, and detect the PRE_NMS threshold crossing bin.
__global__ void __launch_bounds__(256) rewrite_kernel(
        unsigned int* __restrict__ hist,
        unsigned int* __restrict__ binbase,
        const unsigned int* __restrict__ partials,
        unsigned int* __restrict__ thr) {
    int c = blockIdx.x, bb = blockIdx.y, t = threadIdx.x;
    __shared__ unsigned int sp[64];
    __shared__ unsigned int ssum[256];
    if (t < 64) sp[t] = partials[bb * 64 + t];
    unsigned int* h = hist + (size_t)bb * NBIN + c * 1024;
    unsigned int* bs = binbase + (size_t)bb * NBIN + c * 1024;
    uint4 v = reinterpret_cast<const uint4*>(h)[t];
    ssum[t] = v.x + v.y + v.z + v.w;
    __syncthreads();
    unsigned int chunkBase = 0;
    for (int q = c + 1; q < 64; ++q) chunkBase += sp[q];   // uniform broadcast reads
    for (int off = 1; off < 256; off <<= 1) {
        unsigned int val = (t + off < 256) ? ssum[t + off] : 0u;
        __syncthreads();
        ssum[t] += val;
        __syncthreads();
    }
    unsigned int run = chunkBase + ((t < 255) ? ssum[t + 1] : 0u); // keys strictly above
    unsigned int cnt[4] = {v.x, v.y, v.z, v.w};
    unsigned int offv[4];
    for (int q = 3; q >= 0; --q) {
        offv[q] = run;
        unsigned int newrun = run + cnt[q];
        if (run < (unsigned)PRE_NMS && newrun >= (unsigned)PRE_NMS) {
            thr[bb * 2 + 0] = (unsigned)(c * 1024 + t * 4 + q);
            thr[bb * 2 + 1] = newrun;    // total candidates scattered
        }
        run = newrun;
    }
    uint4 o4 = {offv[0], offv[1], offv[2], offv[3]};
    reinterpret_cast<uint4*>(h)[t] = o4;    // bucket cursors
    reinterpret_cast<uint4*>(bs)[t] = o4;   // immutable bucket starts
}

// 3) compact: scatter passing keys into their bin's bucket.
__global__ void __launch_bounds__(256) compact_kernel(
        const float* __restrict__ scores_map,
        const unsigned int* __restrict__ thr,
        unsigned long long* __restrict__ cand,
        unsigned int* __restrict__ hist) {
    int tid = threadIdx.x;
    int gid = blockIdx.x * 256 + tid;        // grid sized exactly: no OOB
    int b = gid / N_;
    int r = gid - b * N_;
    int a = r / LOC;
    int loc = r - a * LOC;
    float sc = scores_map[((size_t)(b * 2 * A_ + A_ + a)) * LOC + loc];
    uint32_t u = f2u(sc);
    uint32_t bin = u >> 16;
    if (bin >= thr[b * 2]) {
        int n = loc * A_ + a;   // reference flat index
        unsigned long long key = ((unsigned long long)u << 18)
                               | (unsigned long long)(N_ - 1 - n);
        unsigned int slot = atomicAdd(&hist[b * NBIN + bin], 1u);
        if (slot < (unsigned)CAP)
            cand[(size_t)b * CAP + slot] = key;
    }
}

// 4) bucket rank + decode: rank = binbase[bin] + (# same-bucket keys greater).
__global__ void __launch_bounds__(256) bucket_decode(
        const unsigned long long* __restrict__ cand,
        const unsigned int* __restrict__ hist,     // bucket ends after compact
        const unsigned int* __restrict__ binbase,  // bucket starts
        const unsigned int* __restrict__ thr,
        const float* __restrict__ bbox_frame,
        const float* __restrict__ im_info,
        const float* __restrict__ anchors,
        float* __restrict__ sortedBox) {
    int gid = blockIdx.x * 256 + threadIdx.x;
    int bb = gid / CAP;
    int i = gid - bb * CAP;
    int count = (int)thr[bb * 2 + 1];
    if (count > CAP) count = CAP;
    if (i >= count) return;
    const unsigned long long* cb = cand + (size_t)bb * CAP;
    unsigned long long me = cb[i];
    int bin = (int)(me >> 34);
    int start = (int)binbase[bb * NBIN + bin];
    int end = (int)hist[bb * NBIN + bin];
    if (end > count) end = count;
    int rank = start;
    for (int q = start; q < end; ++q)
        rank += (cb[q] > me);
    if (rank >= PRE_NMS) return;

    uint32_t u = (uint32_t)(me >> 18);
    int n = N_ - 1 - (int)(me & 0x3FFFFull);
    int a = n % A_;
    int loc = n / A_;
    int k = loc % T_;
    int j = (loc / T_) % W_;
    int ii = loc / (T_ * W_);

    float ax1 = anchors[a * 6 + 0] + (float)(FEAT_STRIDE * j);
    float ay1 = anchors[a * 6 + 1] + (float)(FEAT_STRIDE * ii);
    float az1 = anchors[a * 6 + 2] + (float)k;
    float ax2 = anchors[a * 6 + 3] + (float)(FEAT_STRIDE * j);
    float ay2 = anchors[a * 6 + 4] + (float)(FEAT_STRIDE * ii);
    float az2 = anchors[a * 6 + 5] + (float)k;
    float aw = ax2 - ax1 + 1.0f, ah = ay2 - ay1 + 1.0f, al = az2 - az1 + 1.0f;
    float acx = ax1 + 0.5f * aw, acy = ay1 + 0.5f * ah, acz = az1 + 0.5f * al;

    const float* dp = bbox_frame + ((size_t)(bb * 6 * A_ + a * 6)) * LOC
                    + ii * (W_ * T_) + j * T_ + k;
    float d0 = dp[0 * LOC], d1 = dp[1 * LOC], d2 = dp[2 * LOC];
    float d3 = dp[3 * LOC], d4 = dp[4 * LOC], d5 = dp[5 * LOC];

    float pcx = d0 * aw + acx, pcy = d1 * ah + acy, pcz = d2 * al + acz;
    float pw = expf(d3) * aw, ph = expf(d4) * ah, pl = expf(d5) * al;

    float x1 = pcx - 0.5f * pw, y1 = pcy - 0.5f * ph, z1 = pcz - 0.5f * pl;
    float x2 = pcx + 0.5f * pw, y2 = pcy + 0.5f * ph, z2 = pcz + 0.5f * pl;

    float lx = im_info[1] - 1.0f, ly = im_info[0] - 1.0f, lz = im_info[2] - 1.0f;
    x1 = fminf(fmaxf(x1, 0.0f), lx); y1 = fminf(fmaxf(y1, 0.0f), ly); z1 = fminf(fmaxf(z1, 0.0f), lz);
    x2 = fminf(fmaxf(x2, 0.0f), lx); y2 = fminf(fmaxf(y2, 0.0f), ly); z2 = fminf(fmaxf(z2, 0.0f), lz);

    float vol = (x2 - x1 + 1.0f) * (y2 - y1 + 1.0f) * (z2 - z1 + 1.0f);
    float* p = sortedBox + ((size_t)bb * ROWS + rank) * 8;
    p[0] = x1; p[1] = y1; p[2] = z1; p[3] = x2;
    p[4] = y2; p[5] = z2; p[6] = vol; p[7] = u2f(u);
}

// 5) IoU bitmask: mask[bb][i][w] bit b = (j=64w+b > i) && IoU(i,j) > TH
//    Diagonal band (words g, g+1 of each row) also stored to diagBand[row][0..1].
__global__ void mask_build(const float* __restrict__ sortedBox,
                           unsigned long long* __restrict__ mask,
                           unsigned long long* __restrict__ diagBand) {
    int g = blockIdx.x / NW, w = blockIdx.x % NW;
    if (w < g) return;                      // only need upper triangle words
    int bb = blockIdx.y;
    int lane = threadIdx.x;                 // 64 threads
    __shared__ float colb[64][7];           // x1,y1,z1,x2,y2,z2,vol
    const float* sb = sortedBox + (size_t)bb * ROWS * 8;
    int col = w * 64 + lane;
    if (col < PRE_NMS) {
        const float4* cp4 = reinterpret_cast<const float4*>(sb + (size_t)col * 8);
        float4 lo = cp4[0], hi = cp4[1];
        colb[lane][0] = lo.x; colb[lane][1] = lo.y; colb[lane][2] = lo.z;
        colb[lane][3] = lo.w; colb[lane][4] = hi.x; colb[lane][5] = hi.y;
        colb[lane][6] = hi.z;
    } else {
        colb[lane][0] = 3e8f; colb[lane][1] = 0.f; colb[lane][2] = 0.f;
        colb[lane][3] = -3e8f; colb[lane][4] = 0.f; colb[lane][5] = 0.f;
        colb[lane][6] = 1.0f;
    }
    __syncthreads();
    int row = g * 64 + lane;
    if (row >= PRE_NMS) return;
    const float4* rp4 = reinterpret_cast<const float4*>(sb + (size_t)row * 8);
    float4 rlo = rp4[0], rhi = rp4[1];
    float x1 = rlo.x, y1 = rlo.y, z1 = rlo.z;
    float x2 = rlo.w, y2 = rhi.x, z2 = rhi.y, v = rhi.z;
    unsigned long long word = 0;
    for (int b2 = 0; b2 < 64; ++b2) {
        float iw = fminf(x2, colb[b2][3]) - fmaxf(x1, colb[b2][0]) + 1.0f;
        float ih = fminf(y2, colb[b2][4]) - fmaxf(y1, colb[b2][1]) + 1.0f;
        float il = fminf(z2, colb[b2][5]) - fmaxf(z1, colb[b2][2]) + 1.0f;
        iw = fmaxf(iw, 0.0f); ih = fmaxf(ih, 0.0f); il = fmaxf(il, 0.0f);
        float inter = iw * ih * il;
        float iou = inter / (v + colb[b2][6] - inter);
        int cidx = w * 64 + b2;
        if (cidx > row && iou > NMS_TH) word |= (1ull << b2);
    }
    mask[((size_t)bb * ROWS + row) * NW + w] = word;
    if (w == g) {
        diagBand[((size_t)bb * ROWS + row) * 2 + 0] = word;
        if (g == NW - 1) diagBand[((size_t)bb * ROWS + row) * 2 + 1] = 0ull;
    }
    if (w == g + 1) diagBand[((size_t)bb * ROWS + row) * 2 + 1] = word;
}

// 6) pipelined greedy suppress: ONE barrier per chunk, no HBM round-trip on the
//    critical path. Wave0 scans chunk c (diag band prefetched a chunk ahead;
//    chunk-(c)'s effect on word c+1 carried in registers via band word 1);
//    waves 1..15 concurrently apply chunk-(c-1)'s kept rows to remv[>=c+1] and
//    write their output rows.
__global__ void __launch_bounds__(1024) suppress_kernel(
        const unsigned long long* __restrict__ mask,
        const unsigned long long* __restrict__ diagBand,
        const float* __restrict__ sortedBox,
        float* __restrict__ out) {
    int bb = blockIdx.x;
    int tid = threadIdx.x;
    int lane = tid & 63;
    __shared__ unsigned long long remv[NW];
    __shared__ int kr[2][64];
    __shared__ int s_nk;
    for (int i = tid; i < NW; i += 1024) remv[i] = 0ull;
    if (tid == 0) {
        remv[NW - 1] = ~((1ull << (PRE_NMS - (NW - 1) * 64)) - 1ull);
        s_nk = 0;
    }
    __syncthreads();

    const unsigned long long* M = mask + (size_t)bb * ROWS * NW;
    const unsigned long long* D = diagBand + (size_t)bb * ROWS * 2;
    const float* sb = sortedBox + (size_t)bb * ROWS * 8;
    float* ob = out + (size_t)bb * POST_NMS * 7;

    int kept_total = 0, prev_nk = 0, prev_base = 0, cur = 0;
    unsigned long long diag0 = 0, band1 = 0, sup = 0;
    if (tid < 64) {                       // prologue: load chunk-0 band
        diag0 = D[lane * 2 + 0];
        band1 = D[lane * 2 + 1];
    }

    for (int c = 0; c < NW; ++c) {
        unsigned long long nxt0 = 0, nxt1 = 0;
        if (tid < 64) {
            if (c + 1 < NW) {             // prefetch next chunk's band (hidden)
                nxt0 = D[((c + 1) * 64 + lane) * 2 + 0];
                nxt1 = D[((c + 1) * 64 + lane) * 2 + 1];
            }
            // serial scan of word c
            unsigned long long alive = ~(remv[c] | sup);
            unsigned long long supn = 0;
            int nk = 0;
            while (alive && kept_total + nk < POST_NMS) {
                int b = __builtin_ctzll(alive);
                if (lane == 0) kr[cur][nk] = c * 64 + b;
                ++nk;
                alive &= ~(__shfl(diag0, b) | (1ull << b));
                supn |= __shfl(band1, b);
            }
            sup = supn;
            if (tid == 0) s_nk = nk;
        } else {
            // background: apply chunk-(c-1) kept rows to words >= c+1, write outputs
            int t = tid - 64;
            for (int w2 = c + 1 + t; w2 < NW; w2 += 960) {
                unsigned long long v = remv[w2];
                for (int i = 0; i < prev_nk; ++i)
                    v |= M[(size_t)kr[cur ^ 1][i] * NW + w2];
                remv[w2] = v;
            }
            for (int e = t; e < prev_nk * 7; e += 960) {
                int i = e / 7, j = e - i * 7;
                ob[(size_t)(prev_base + i) * 7 + j] =
                    sb[(size_t)kr[cur ^ 1][i] * 8 + (j == 0 ? 7 : j - 1)];
            }
        }
        __syncthreads();
        int nk = s_nk;
        prev_base = kept_total;
        kept_total += nk;
        prev_nk = nk;
        cur ^= 1;
        if (tid < 64) { diag0 = nxt0; band1 = nxt1; }
        if (kept_total >= POST_NMS) break;
    }
    // flush outputs of the final scanned chunk (its bg pass never ran)
    for (int e = tid; e < prev_nk * 7; e += 1024) {
        int i = e / 7, j = e - i * 7;
        ob[(size_t)(prev_base + i) * 7 + j] =
            sb[(size_t)kr[cur ^ 1][i] * 8 + (j == 0 ? 7 : j - 1)];
    }
    for (int idx = kept_total * 7 + tid; idx < POST_NMS * 7; idx += 1024)
        ob[idx] = 0.0f;
}

extern "C" void kernel_launch(void* const* d_in, const int* in_sizes, int n_in,
                              void* d_out, int out_size, void* d_ws, size_t ws_size,
                              hipStream_t stream) {
    const float* scores_map = (const float*)d_in[0];
    const float* bbox_frame = (const float*)d_in[1];
    const float* im_info    = (const float*)d_in[2];
    const float* anchors    = (const float*)d_in[3];
    float* out = (float*)d_out;

    // workspace layout (bytes) — total 10,088,976 (same as round 7)
    char* ws = (char*)d_ws;
    unsigned long long* mask     = (unsigned long long*)(ws + 0);          // 9,048,064
    unsigned int* binbase        = (unsigned int*)(ws + 0);                // aliases mask
                                                                           // (dead before mask_build) 524,288
    float* sortedBox             = (float*)(ws + 9048064);                 // 385,024
    unsigned long long* cand     = (unsigned long long*)(ws + 9433088);    // 131,072
    unsigned int* hist           = (unsigned int*)(ws + 9564160);          // 524,288
    unsigned long long* diagBand = (unsigned long long*)(ws + 9564160);    // aliases hist
                                                                           // (hist dead after decode) 192,512
    unsigned int* thr            = (unsigned int*)(ws + 10088448);         // 16
    unsigned int* partials       = (unsigned int*)(ws + 10088464);         // 512

    hipMemsetAsync(hist, 0, 524288, stream);

    int total = B_ * N_;
    hist_kernel<<<(total + 255) / 256, 256, 0, stream>>>(scores_map, hist);
    partial_kernel<<<dim3(64, B_), 256, 0, stream>>>(hist, partials);
    rewrite_kernel<<<dim3(64, B_), 256, 0, stream>>>(hist, binbase, partials, thr);
    compact_kernel<<<total / 256, 256, 0, stream>>>(scores_map, thr, cand, hist);
    bucket_decode<<<B_ * CAP / 256, 256, 0, stream>>>(cand, hist, binbase, thr,
                                                      bbox_frame, im_info, anchors,
                                                      sortedBox);
    mask_build<<<dim3(NW * NW, B_), 64, 0, stream>>>(sortedBox, mask, diagBand);
    suppress_kernel<<<B_, 1024, 0, stream>>>(mask, diagBand, sortedBox, out);
}

// Round 9
// 144.255 us; speedup vs baseline: 2.3192x; 1.2924x over previous
//
#include <hip/hip_runtime.h>
#include <stdint.h>

#define FEAT_STRIDE 16
#define PRE_NMS 6000
#define POST_NMS 300
#define NMS_TH 0.7f

static constexpr int B_ = 2, A_ = 9, H_ = 32, W_ = 32, T_ = 16;
static constexpr int LOC = H_ * W_ * T_;   // 16384
static constexpr int N_ = LOC * A_;        // 147456
static constexpr int NBIN = 65536;
static constexpr int NREP = 8;             // histogram replicas (1 per XCD)
static constexpr int CAP = 8192;           // candidate capacity per batch
static constexpr int NW = 94;              // ceil(6000/64) mask words per row
static constexpr int ROWS = 6016;          // NW*64 padded rows

// sortedBox row layout (8 floats, 32B aligned): [x1,y1,z1,x2, y2,z2,vol,score]

// ---- float <-> monotonic u32 key ----
__device__ __forceinline__ uint32_t f2u(float f) {
    uint32_t b = __float_as_uint(f);
    return b ^ ((b >> 31) ? 0xFFFFFFFFu : 0x80000000u);
}
__device__ __forceinline__ float u2f(uint32_t u) {
    uint32_t b = (u >> 31) ? (u ^ 0x80000000u) : ~u;
    return __uint_as_float(b);
}

// 1) replicated histogram of score keys' top-16 bits.
//    rep = blockIdx & 7 ~ XCD id (round-robin dispatch) -> atomics stay in local L2.
__global__ void hist_kernel(const float* __restrict__ scores_map,
                            unsigned int* __restrict__ histR) {
    int gid = blockIdx.x * blockDim.x + threadIdx.x;
    if (gid >= B_ * N_) return;
    int b = gid / N_;
    int r = gid - b * N_;
    int a = r / LOC;
    int loc = r - a * LOC;
    float sc = scores_map[((size_t)(b * 2 * A_ + A_ + a)) * LOC + loc];
    uint32_t u = f2u(sc);
    int rep = blockIdx.x & (NREP - 1);
    atomicAdd(&histR[((size_t)(rep * B_ + b)) * NBIN + (u >> 16)], 1u);
}

// 2a) per (batch, 1024-bin chunk): block-reduce chunk count over all replicas
__global__ void __launch_bounds__(256) partial_kernel(
        const unsigned int* __restrict__ histR,
        unsigned int* __restrict__ partials) {
    int c = blockIdx.x, bb = blockIdx.y, t = threadIdx.x;
    unsigned int s = 0;
#pragma unroll
    for (int r = 0; r < NREP; ++r) {
        const uint4* h4 = reinterpret_cast<const uint4*>(
            histR + ((size_t)(r * B_ + bb)) * NBIN + c * 1024);
        uint4 v = h4[t];
        s += v.x + v.y + v.z + v.w;
    }
    __shared__ unsigned int red[256];
    red[t] = s;
    __syncthreads();
    for (int off = 128; off > 0; off >>= 1) {
        if (t < off) red[t] += red[t + off];
        __syncthreads();
    }
    if (t == 0) partials[bb * 64 + c] = red[0];
}

// 2b) per (batch, chunk): fold replicas -> per-bin counts, rewrite to suffix
//     offsets (bucket starts) in canonical hist + binbase, detect threshold bin.
__global__ void __launch_bounds__(256) rewrite_kernel(
        const unsigned int* __restrict__ histR,
        unsigned int* __restrict__ hist,
        unsigned int* __restrict__ binbase,
        const unsigned int* __restrict__ partials,
        unsigned int* __restrict__ thr) {
    int c = blockIdx.x, bb = blockIdx.y, t = threadIdx.x;
    __shared__ unsigned int sp[64];
    __shared__ unsigned int ssum[256];
    if (t < 64) sp[t] = partials[bb * 64 + t];
    uint4 v = {0u, 0u, 0u, 0u};
#pragma unroll
    for (int r = 0; r < NREP; ++r) {
        const uint4* h4 = reinterpret_cast<const uint4*>(
            histR + ((size_t)(r * B_ + bb)) * NBIN + c * 1024);
        uint4 w = h4[t];
        v.x += w.x; v.y += w.y; v.z += w.z; v.w += w.w;
    }
    unsigned int* h = hist + (size_t)bb * NBIN + c * 1024;
    unsigned int* bs = binbase + (size_t)bb * NBIN + c * 1024;
    ssum[t] = v.x + v.y + v.z + v.w;
    __syncthreads();
    unsigned int chunkBase = 0;
    for (int q = c + 1; q < 64; ++q) chunkBase += sp[q];   // uniform broadcast reads
    for (int off = 1; off < 256; off <<= 1) {
        unsigned int val = (t + off < 256) ? ssum[t + off] : 0u;
        __syncthreads();
        ssum[t] += val;
        __syncthreads();
    }
    unsigned int run = chunkBase + ((t < 255) ? ssum[t + 1] : 0u); // keys strictly above
    unsigned int cnt[4] = {v.x, v.y, v.z, v.w};
    unsigned int offv[4];
    for (int q = 3; q >= 0; --q) {
        offv[q] = run;
        unsigned int newrun = run + cnt[q];
        if (run < (unsigned)PRE_NMS && newrun >= (unsigned)PRE_NMS) {
            thr[bb * 2 + 0] = (unsigned)(c * 1024 + t * 4 + q);
            thr[bb * 2 + 1] = newrun;    // total candidates scattered
        }
        run = newrun;
    }
    uint4 o4 = {offv[0], offv[1], offv[2], offv[3]};
    reinterpret_cast<uint4*>(h)[t] = o4;    // bucket cursors
    reinterpret_cast<uint4*>(bs)[t] = o4;   // immutable bucket starts
}

// 3) compact: scatter passing keys into their bin's bucket.
__global__ void __launch_bounds__(256) compact_kernel(
        const float* __restrict__ scores_map,
        const unsigned int* __restrict__ thr,
        unsigned long long* __restrict__ cand,
        unsigned int* __restrict__ hist) {
    int tid = threadIdx.x;
    int gid = blockIdx.x * 256 + tid;        // grid sized exactly: no OOB
    int b = gid / N_;
    int r = gid - b * N_;
    int a = r / LOC;
    int loc = r - a * LOC;
    float sc = scores_map[((size_t)(b * 2 * A_ + A_ + a)) * LOC + loc];
    uint32_t u = f2u(sc);
    uint32_t bin = u >> 16;
    if (bin >= thr[b * 2]) {
        int n = loc * A_ + a;   // reference flat index
        unsigned long long key = ((unsigned long long)u << 18)
                               | (unsigned long long)(N_ - 1 - n);
        unsigned int slot = atomicAdd(&hist[b * NBIN + bin], 1u);
        if (slot < (unsigned)CAP)
            cand[(size_t)b * CAP + slot] = key;
    }
}

// 4) bucket rank + decode: rank = binbase[bin] + (# same-bucket keys greater).
__global__ void __launch_bounds__(256) bucket_decode(
        const unsigned long long* __restrict__ cand,
        const unsigned int* __restrict__ hist,     // bucket ends after compact
        const unsigned int* __restrict__ binbase,  // bucket starts
        const unsigned int* __restrict__ thr,
        const float* __restrict__ bbox_frame,
        const float* __restrict__ im_info,
        const float* __restrict__ anchors,
        float* __restrict__ sortedBox) {
    int gid = blockIdx.x * 256 + threadIdx.x;
    int bb = gid / CAP;
    int i = gid - bb * CAP;
    int count = (int)thr[bb * 2 + 1];
    if (count > CAP) count = CAP;
    if (i >= count) return;
    const unsigned long long* cb = cand + (size_t)bb * CAP;
    unsigned long long me = cb[i];
    int bin = (int)(me >> 34);
    int start = (int)binbase[bb * NBIN + bin];
    int end = (int)hist[bb * NBIN + bin];
    if (end > count) end = count;
    int rank = start;
    for (int q = start; q < end; ++q)
        rank += (cb[q] > me);
    if (rank >= PRE_NMS) return;

    uint32_t u = (uint32_t)(me >> 18);
    int n = N_ - 1 - (int)(me & 0x3FFFFull);
    int a = n % A_;
    int loc = n / A_;
    int k = loc % T_;
    int j = (loc / T_) % W_;
    int ii = loc / (T_ * W_);

    float ax1 = anchors[a * 6 + 0] + (float)(FEAT_STRIDE * j);
    float ay1 = anchors[a * 6 + 1] + (float)(FEAT_STRIDE * ii);
    float az1 = anchors[a * 6 + 2] + (float)k;
    float ax2 = anchors[a * 6 + 3] + (float)(FEAT_STRIDE * j);
    float ay2 = anchors[a * 6 + 4] + (float)(FEAT_STRIDE * ii);
    float az2 = anchors[a * 6 + 5] + (float)k;
    float aw = ax2 - ax1 + 1.0f, ah = ay2 - ay1 + 1.0f, al = az2 - az1 + 1.0f;
    float acx = ax1 + 0.5f * aw, acy = ay1 + 0.5f * ah, acz = az1 + 0.5f * al;

    const float* dp = bbox_frame + ((size_t)(bb * 6 * A_ + a * 6)) * LOC
                    + ii * (W_ * T_) + j * T_ + k;
    float d0 = dp[0 * LOC], d1 = dp[1 * LOC], d2 = dp[2 * LOC];
    float d3 = dp[3 * LOC], d4 = dp[4 * LOC], d5 = dp[5 * LOC];

    float pcx = d0 * aw + acx, pcy = d1 * ah + acy, pcz = d2 * al + acz;
    float pw = expf(d3) * aw, ph = expf(d4) * ah, pl = expf(d5) * al;

    float x1 = pcx - 0.5f * pw, y1 = pcy - 0.5f * ph, z1 = pcz - 0.5f * pl;
    float x2 = pcx + 0.5f * pw, y2 = pcy + 0.5f * ph, z2 = pcz + 0.5f * pl;

    float lx = im_info[1] - 1.0f, ly = im_info[0] - 1.0f, lz = im_info[2] - 1.0f;
    x1 = fminf(fmaxf(x1, 0.0f), lx); y1 = fminf(fmaxf(y1, 0.0f), ly); z1 = fminf(fmaxf(z1, 0.0f), lz);
    x2 = fminf(fmaxf(x2, 0.0f), lx); y2 = fminf(fmaxf(y2, 0.0f), ly); z2 = fminf(fmaxf(z2, 0.0f), lz);

    float vol = (x2 - x1 + 1.0f) * (y2 - y1 + 1.0f) * (z2 - z1 + 1.0f);
    float* p = sortedBox + ((size_t)bb * ROWS + rank) * 8;
    p[0] = x1; p[1] = y1; p[2] = z1; p[3] = x2;
    p[4] = y2; p[5] = z2; p[6] = vol; p[7] = u2f(u);
}

// 5) IoU bitmask: mask[bb][i][w] bit b = (j=64w+b > i) && IoU(i,j) > TH
//    Diagonal band (words g, g+1 of each row) also stored to diagBand[row][0..1].
__global__ void mask_build(const float* __restrict__ sortedBox,
                           unsigned long long* __restrict__ mask,
                           unsigned long long* __restrict__ diagBand) {
    int g = blockIdx.x / NW, w = blockIdx.x % NW;
    if (w < g) return;                      // only need upper triangle words
    int bb = blockIdx.y;
    int lane = threadIdx.x;                 // 64 threads
    __shared__ float colb[64][7];           // x1,y1,z1,x2,y2,z2,vol
    const float* sb = sortedBox + (size_t)bb * ROWS * 8;
    int col = w * 64 + lane;
    if (col < PRE_NMS) {
        const float4* cp4 = reinterpret_cast<const float4*>(sb + (size_t)col * 8);
        float4 lo = cp4[0], hi = cp4[1];
        colb[lane][0] = lo.x; colb[lane][1] = lo.y; colb[lane][2] = lo.z;
        colb[lane][3] = lo.w; colb[lane][4] = hi.x; colb[lane][5] = hi.y;
        colb[lane][6] = hi.z;
    } else {
        colb[lane][0] = 3e8f; colb[lane][1] = 0.f; colb[lane][2] = 0.f;
        colb[lane][3] = -3e8f; colb[lane][4] = 0.f; colb[lane][5] = 0.f;
        colb[lane][6] = 1.0f;
    }
    __syncthreads();
    int row = g * 64 + lane;
    if (row >= PRE_NMS) return;
    const float4* rp4 = reinterpret_cast<const float4*>(sb + (size_t)row * 8);
    float4 rlo = rp4[0], rhi = rp4[1];
    float x1 = rlo.x, y1 = rlo.y, z1 = rlo.z;
    float x2 = rlo.w, y2 = rhi.x, z2 = rhi.y, v = rhi.z;
    unsigned long long word = 0;
    for (int b2 = 0; b2 < 64; ++b2) {
        float iw = fminf(x2, colb[b2][3]) - fmaxf(x1, colb[b2][0]) + 1.0f;
        float ih = fminf(y2, colb[b2][4]) - fmaxf(y1, colb[b2][1]) + 1.0f;
        float il = fminf(z2, colb[b2][5]) - fmaxf(z1, colb[b2][2]) + 1.0f;
        iw = fmaxf(iw, 0.0f); ih = fmaxf(ih, 0.0f); il = fmaxf(il, 0.0f);
        float inter = iw * ih * il;
        float iou = inter / (v + colb[b2][6] - inter);
        int cidx = w * 64 + b2;
        if (cidx > row && iou > NMS_TH) word |= (1ull << b2);
    }
    mask[((size_t)bb * ROWS + row) * NW + w] = word;
    if (w == g) {
        diagBand[((size_t)bb * ROWS + row) * 2 + 0] = word;
        if (g == NW - 1) diagBand[((size_t)bb * ROWS + row) * 2 + 1] = 0ull;
    }
    if (w == g + 1) diagBand[((size_t)bb * ROWS + row) * 2 + 1] = word;
}

// 6) pipelined greedy suppress: ONE barrier per chunk, no HBM round-trip on the
//    critical path. Wave0 scans chunk c (diag band prefetched a chunk ahead;
//    chunk-(c)'s effect on word c+1 carried in registers via band word 1);
//    waves 1..15 concurrently apply chunk-(c-1)'s kept rows to remv[>=c+1] and
//    write their output rows.
__global__ void __launch_bounds__(1024) suppress_kernel(
        const unsigned long long* __restrict__ mask,
        const unsigned long long* __restrict__ diagBand,
        const float* __restrict__ sortedBox,
        float* __restrict__ out) {
    int bb = blockIdx.x;
    int tid = threadIdx.x;
    int lane = tid & 63;
    __shared__ unsigned long long remv[NW];
    __shared__ int kr[2][64];
    __shared__ int s_nk;
    for (int i = tid; i < NW; i += 1024) remv[i] = 0ull;
    if (tid == 0) {
        remv[NW - 1] = ~((1ull << (PRE_NMS - (NW - 1) * 64)) - 1ull);
        s_nk = 0;
    }
    __syncthreads();

    const unsigned long long* M = mask + (size_t)bb * ROWS * NW;
    const unsigned long long* D = diagBand + (size_t)bb * ROWS * 2;
    const float* sb = sortedBox + (size_t)bb * ROWS * 8;
    float* ob = out + (size_t)bb * POST_NMS * 7;

    int kept_total = 0, prev_nk = 0, prev_base = 0, cur = 0;
    unsigned long long diag0 = 0, band1 = 0, sup = 0;
    if (tid < 64) {                       // prologue: load chunk-0 band
        diag0 = D[lane * 2 + 0];
        band1 = D[lane * 2 + 1];
    }

    for (int c = 0; c < NW; ++c) {
        unsigned long long nxt0 = 0, nxt1 = 0;
        if (tid < 64) {
            if (c + 1 < NW) {             // prefetch next chunk's band (hidden)
                nxt0 = D[((c + 1) * 64 + lane) * 2 + 0];
                nxt1 = D[((c + 1) * 64 + lane) * 2 + 1];
            }
            // serial scan of word c
            unsigned long long alive = ~(remv[c] | sup);
            unsigned long long supn = 0;
            int nk = 0;
            while (alive && kept_total + nk < POST_NMS) {
                int b = __builtin_ctzll(alive);
                if (lane == 0) kr[cur][nk] = c * 64 + b;
                ++nk;
                alive &= ~(__shfl(diag0, b) | (1ull << b));
                supn |= __shfl(band1, b);
            }
            sup = supn;
            if (tid == 0) s_nk = nk;
        } else {
            // background: apply chunk-(c-1) kept rows to words >= c+1, write outputs
            int t = tid - 64;
            for (int w2 = c + 1 + t; w2 < NW; w2 += 960) {
                unsigned long long v = remv[w2];
                for (int i = 0; i < prev_nk; ++i)
                    v |= M[(size_t)kr[cur ^ 1][i] * NW + w2];
                remv[w2] = v;
            }
            for (int e = t; e < prev_nk * 7; e += 960) {
                int i = e / 7, j = e - i * 7;
                ob[(size_t)(prev_base + i) * 7 + j] =
                    sb[(size_t)kr[cur ^ 1][i] * 8 + (j == 0 ? 7 : j - 1)];
            }
        }
        __syncthreads();
        int nk = s_nk;
        prev_base = kept_total;
        kept_total += nk;
        prev_nk = nk;
        cur ^= 1;
        if (tid < 64) { diag0 = nxt0; band1 = nxt1; }
        if (kept_total >= POST_NMS) break;
    }
    // flush outputs of the final scanned chunk (its bg pass never ran)
    for (int e = tid; e < prev_nk * 7; e += 1024) {
        int i = e / 7, j = e - i * 7;
        ob[(size_t)(prev_base + i) * 7 + j] =
            sb[(size_t)kr[cur ^ 1][i] * 8 + (j == 0 ? 7 : j - 1)];
    }
    for (int idx = kept_total * 7 + tid; idx < POST_NMS * 7; idx += 1024)
        ob[idx] = 0.0f;
}

extern "C" void kernel_launch(void* const* d_in, const int* in_sizes, int n_in,
                              void* d_out, int out_size, void* d_ws, size_t ws_size,
                              hipStream_t stream) {
    const float* scores_map = (const float*)d_in[0];
    const float* bbox_frame = (const float*)d_in[1];
    const float* im_info    = (const float*)d_in[2];
    const float* anchors    = (const float*)d_in[3];
    float* out = (float*)d_out;

    // workspace layout (bytes) — total 10,088,976 (same footprint as round 7/8)
    char* ws = (char*)d_ws;
    unsigned long long* mask     = (unsigned long long*)(ws + 0);          // 9,048,064
    unsigned int* binbase        = (unsigned int*)(ws + 0);                // aliases mask
                                                                           // (dead before mask_build) 524,288
    unsigned int* histR          = (unsigned int*)(ws + 524288);           // aliases mask
                                                                           // 8 replicas: 4,194,304
    float* sortedBox             = (float*)(ws + 9048064);                 // 385,024
    unsigned long long* cand     = (unsigned long long*)(ws + 9433088);    // 131,072
    unsigned int* hist           = (unsigned int*)(ws + 9564160);          // 524,288 canonical
    unsigned long long* diagBand = (unsigned long long*)(ws + 9564160);    // aliases hist
                                                                           // (hist dead after decode) 192,512
    unsigned int* thr            = (unsigned int*)(ws + 10088448);         // 16
    unsigned int* partials       = (unsigned int*)(ws + 10088464);         // 512

    hipMemsetAsync(histR, 0, (size_t)NREP * B_ * NBIN * 4, stream);

    int total = B_ * N_;
    hist_kernel<<<(total + 255) / 256, 256, 0, stream>>>(scores_map, histR);
    partial_kernel<<<dim3(64, B_), 256, 0, stream>>>(histR, partials);
    rewrite_kernel<<<dim3(64, B_), 256, 0, stream>>>(histR, hist, binbase, partials, thr);
    compact_kernel<<<total / 256, 256, 0, stream>>>(scores_map, thr, cand, hist);
    bucket_decode<<<B_ * CAP / 256, 256, 0, stream>>>(cand, hist, binbase, thr,
                                                      bbox_frame, im_info, anchors,
                                                      sortedBox);
    mask_build<<<dim3(NW * NW, B_), 64, 0, stream>>>(sortedBox, mask, diagBand);
    suppress_kernel<<<B_, 1024, 0, stream>>>(mask, diagBand, sortedBox, out);
}

// Round 10
// 134.097 us; speedup vs baseline: 2.4949x; 1.0758x over previous
//
#include <hip/hip_runtime.h>
#include <stdint.h>

#define FEAT_STRIDE 16
#define PRE_NMS 6000
#define POST_NMS 300
#define NMS_TH 0.7f

static constexpr int B_ = 2, A_ = 9, H_ = 32, W_ = 32, T_ = 16;
static constexpr int LOC = H_ * W_ * T_;   // 16384
static constexpr int N_ = LOC * A_;        // 147456
static constexpr int NBIN = 65536;
static constexpr int NREP = 8;             // histogram replicas (1 per XCD)
static constexpr int CAP = 8192;           // candidate capacity per batch
static constexpr int NW = 94;              // ceil(6000/64) mask words per row
static constexpr int ROWS = 6016;          // NW*64 padded rows

// Exact threshold: fl32(inter/denom) > 0.7f  <=>  inter >= BMID * denom (real),
// BMID = midpoint(0.7f, nextafter(0.7f)) — tie rounds to even mantissa = next(0.7f).
// BMID has 25 mantissa bits; BMID*(double)denom is exact (25+24 <= 53).
static constexpr double BMID = 0.7000000178813934326171875;

// sortedBox row layout (8 floats, 32B aligned): [x1,y1,z1,x2, y2,z2,vol,score]
// mask layout: [bb][w][row] (transposed) -> mask_build stores coalesce.

// ---- float <-> monotonic u32 key ----
__device__ __forceinline__ uint32_t f2u(float f) {
    uint32_t b = __float_as_uint(f);
    return b ^ ((b >> 31) ? 0xFFFFFFFFu : 0x80000000u);
}
__device__ __forceinline__ float u2f(uint32_t u) {
    uint32_t b = (u >> 31) ? (u ^ 0x80000000u) : ~u;
    return __uint_as_float(b);
}

// 1) replicated histogram of score keys' top-16 bits.
__global__ void hist_kernel(const float* __restrict__ scores_map,
                            unsigned int* __restrict__ histR) {
    int gid = blockIdx.x * blockDim.x + threadIdx.x;
    if (gid >= B_ * N_) return;
    int b = gid / N_;
    int r = gid - b * N_;
    int a = r / LOC;
    int loc = r - a * LOC;
    float sc = scores_map[((size_t)(b * 2 * A_ + A_ + a)) * LOC + loc];
    uint32_t u = f2u(sc);
    int rep = blockIdx.x & (NREP - 1);
    atomicAdd(&histR[((size_t)(rep * B_ + b)) * NBIN + (u >> 16)], 1u);
}

// 2a) per (batch, 1024-bin chunk): block-reduce chunk count over all replicas
__global__ void __launch_bounds__(256) partial_kernel(
        const unsigned int* __restrict__ histR,
        unsigned int* __restrict__ partials) {
    int c = blockIdx.x, bb = blockIdx.y, t = threadIdx.x;
    unsigned int s = 0;
#pragma unroll
    for (int r = 0; r < NREP; ++r) {
        const uint4* h4 = reinterpret_cast<const uint4*>(
            histR + ((size_t)(r * B_ + bb)) * NBIN + c * 1024);
        uint4 v = h4[t];
        s += v.x + v.y + v.z + v.w;
    }
    __shared__ unsigned int red[256];
    red[t] = s;
    __syncthreads();
    for (int off = 128; off > 0; off >>= 1) {
        if (t < off) red[t] += red[t + off];
        __syncthreads();
    }
    if (t == 0) partials[bb * 64 + c] = red[0];
}

// 2b) fold replicas -> suffix offsets (bucket starts) + threshold bin detect
__global__ void __launch_bounds__(256) rewrite_kernel(
        const unsigned int* __restrict__ histR,
        unsigned int* __restrict__ hist,
        unsigned int* __restrict__ binbase,
        const unsigned int* __restrict__ partials,
        unsigned int* __restrict__ thr) {
    int c = blockIdx.x, bb = blockIdx.y, t = threadIdx.x;
    __shared__ unsigned int sp[64];
    __shared__ unsigned int ssum[256];
    if (t < 64) sp[t] = partials[bb * 64 + t];
    uint4 v = {0u, 0u, 0u, 0u};
#pragma unroll
    for (int r = 0; r < NREP; ++r) {
        const uint4* h4 = reinterpret_cast<const uint4*>(
            histR + ((size_t)(r * B_ + bb)) * NBIN + c * 1024);
        uint4 w = h4[t];
        v.x += w.x; v.y += w.y; v.z += w.z; v.w += w.w;
    }
    unsigned int* h = hist + (size_t)bb * NBIN + c * 1024;
    unsigned int* bs = binbase + (size_t)bb * NBIN + c * 1024;
    ssum[t] = v.x + v.y + v.z + v.w;
    __syncthreads();
    unsigned int chunkBase = 0;
    for (int q = c + 1; q < 64; ++q) chunkBase += sp[q];
    for (int off = 1; off < 256; off <<= 1) {
        unsigned int val = (t + off < 256) ? ssum[t + off] : 0u;
        __syncthreads();
        ssum[t] += val;
        __syncthreads();
    }
    unsigned int run = chunkBase + ((t < 255) ? ssum[t + 1] : 0u);
    unsigned int cnt[4] = {v.x, v.y, v.z, v.w};
    unsigned int offv[4];
    for (int q = 3; q >= 0; --q) {
        offv[q] = run;
        unsigned int newrun = run + cnt[q];
        if (run < (unsigned)PRE_NMS && newrun >= (unsigned)PRE_NMS) {
            thr[bb * 2 + 0] = (unsigned)(c * 1024 + t * 4 + q);
            thr[bb * 2 + 1] = newrun;
        }
        run = newrun;
    }
    uint4 o4 = {offv[0], offv[1], offv[2], offv[3]};
    reinterpret_cast<uint4*>(h)[t] = o4;    // bucket cursors
    reinterpret_cast<uint4*>(bs)[t] = o4;   // immutable bucket starts
}

// 3) compact: scatter passing keys into their bin's bucket.
__global__ void __launch_bounds__(256) compact_kernel(
        const float* __restrict__ scores_map,
        const unsigned int* __restrict__ thr,
        unsigned long long* __restrict__ cand,
        unsigned int* __restrict__ hist) {
    int tid = threadIdx.x;
    int gid = blockIdx.x * 256 + tid;
    int b = gid / N_;
    int r = gid - b * N_;
    int a = r / LOC;
    int loc = r - a * LOC;
    float sc = scores_map[((size_t)(b * 2 * A_ + A_ + a)) * LOC + loc];
    uint32_t u = f2u(sc);
    uint32_t bin = u >> 16;
    if (bin >= thr[b * 2]) {
        int n = loc * A_ + a;
        unsigned long long key = ((unsigned long long)u << 18)
                               | (unsigned long long)(N_ - 1 - n);
        unsigned int slot = atomicAdd(&hist[b * NBIN + bin], 1u);
        if (slot < (unsigned)CAP)
            cand[(size_t)b * CAP + slot] = key;
    }
}

// 4) bucket rank + decode: rank = binbase[bin] + (# same-bucket keys greater).
__global__ void __launch_bounds__(256) bucket_decode(
        const unsigned long long* __restrict__ cand,
        const unsigned int* __restrict__ hist,
        const unsigned int* __restrict__ binbase,
        const unsigned int* __restrict__ thr,
        const float* __restrict__ bbox_frame,
        const float* __restrict__ im_info,
        const float* __restrict__ anchors,
        float* __restrict__ sortedBox) {
    int gid = blockIdx.x * 256 + threadIdx.x;
    int bb = gid / CAP;
    int i = gid - bb * CAP;
    int count = (int)thr[bb * 2 + 1];
    if (count > CAP) count = CAP;
    if (i >= count) return;
    const unsigned long long* cb = cand + (size_t)bb * CAP;
    unsigned long long me = cb[i];
    int bin = (int)(me >> 34);
    int start = (int)binbase[bb * NBIN + bin];
    int end = (int)hist[bb * NBIN + bin];
    if (end > count) end = count;
    int rank = start;
    for (int q = start; q < end; ++q)
        rank += (cb[q] > me);
    if (rank >= PRE_NMS) return;

    uint32_t u = (uint32_t)(me >> 18);
    int n = N_ - 1 - (int)(me & 0x3FFFFull);
    int a = n % A_;
    int loc = n / A_;
    int k = loc % T_;
    int j = (loc / T_) % W_;
    int ii = loc / (T_ * W_);

    float ax1 = anchors[a * 6 + 0] + (float)(FEAT_STRIDE * j);
    float ay1 = anchors[a * 6 + 1] + (float)(FEAT_STRIDE * ii);
    float az1 = anchors[a * 6 + 2] + (float)k;
    float ax2 = anchors[a * 6 + 3] + (float)(FEAT_STRIDE * j);
    float ay2 = anchors[a * 6 + 4] + (float)(FEAT_STRIDE * ii);
    float az2 = anchors[a * 6 + 5] + (float)k;
    float aw = ax2 - ax1 + 1.0f, ah = ay2 - ay1 + 1.0f, al = az2 - az1 + 1.0f;
    float acx = ax1 + 0.5f * aw, acy = ay1 + 0.5f * ah, acz = az1 + 0.5f * al;

    const float* dp = bbox_frame + ((size_t)(bb * 6 * A_ + a * 6)) * LOC
                    + ii * (W_ * T_) + j * T_ + k;
    float d0 = dp[0 * LOC], d1 = dp[1 * LOC], d2 = dp[2 * LOC];
    float d3 = dp[3 * LOC], d4 = dp[4 * LOC], d5 = dp[5 * LOC];

    float pcx = d0 * aw + acx, pcy = d1 * ah + acy, pcz = d2 * al + acz;
    float pw = expf(d3) * aw, ph = expf(d4) * ah, pl = expf(d5) * al;

    float x1 = pcx - 0.5f * pw, y1 = pcy - 0.5f * ph, z1 = pcz - 0.5f * pl;
    float x2 = pcx + 0.5f * pw, y2 = pcy + 0.5f * ph, z2 = pcz + 0.5f * pl;

    float lx = im_info[1] - 1.0f, ly = im_info[0] - 1.0f, lz = im_info[2] - 1.0f;
    x1 = fminf(fmaxf(x1, 0.0f), lx); y1 = fminf(fmaxf(y1, 0.0f), ly); z1 = fminf(fmaxf(z1, 0.0f), lz);
    x2 = fminf(fmaxf(x2, 0.0f), lx); y2 = fminf(fmaxf(y2, 0.0f), ly); z2 = fminf(fmaxf(z2, 0.0f), lz);

    float vol = (x2 - x1 + 1.0f) * (y2 - y1 + 1.0f) * (z2 - z1 + 1.0f);
    float* p = sortedBox + ((size_t)bb * ROWS + rank) * 8;
    p[0] = x1; p[1] = y1; p[2] = z1; p[3] = x2;
    p[4] = y2; p[5] = z2; p[6] = vol; p[7] = u2f(u);
}

// 5) IoU bitmask (transposed): mask[bb][w][row] bit b = (j=64w+b > row) && IoU > TH.
//    Column boxes staged as two float4 LDS arrays (2x ds_read_b128 per IoU);
//    division replaced by the exact double compare (bit-identical decisions).
__global__ void mask_build(const float* __restrict__ sortedBox,
                           unsigned long long* __restrict__ mask,
                           unsigned long long* __restrict__ diagBand) {
    int g = blockIdx.x / NW, w = blockIdx.x % NW;
    if (w < g) return;                      // only upper triangle
    int bb = blockIdx.y;
    int lane = threadIdx.x;                 // 64 threads
    __shared__ float4 colA[64];             // x1, y1, z1, x2
    __shared__ float4 colB[64];             // y2, z2, vol, pad
    const float* sb = sortedBox + (size_t)bb * ROWS * 8;
    int col = w * 64 + lane;
    if (col < PRE_NMS) {
        const float4* cp4 = reinterpret_cast<const float4*>(sb + (size_t)col * 8);
        float4 lo = cp4[0], hi = cp4[1];
        colA[lane] = make_float4(lo.x, lo.y, lo.z, lo.w);
        colB[lane] = make_float4(hi.x, hi.y, hi.z, 0.0f);
    } else {
        colA[lane] = make_float4(3e8f, 0.0f, 0.0f, -3e8f);
        colB[lane] = make_float4(0.0f, 0.0f, 1.0f, 0.0f);
    }
    __syncthreads();
    int row = g * 64 + lane;
    if (row >= PRE_NMS) return;
    const float4* rp4 = reinterpret_cast<const float4*>(sb + (size_t)row * 8);
    float4 rlo = rp4[0], rhi = rp4[1];
    float x1 = rlo.x, y1 = rlo.y, z1 = rlo.z;
    float x2 = rlo.w, y2 = rhi.x, z2 = rhi.y, v = rhi.z;
    unsigned long long word = 0;
#pragma unroll 8
    for (int b2 = 0; b2 < 64; ++b2) {
        float4 cA = colA[b2];               // broadcast ds_read_b128
        float4 cB = colB[b2];
        float iw = fminf(x2, cA.w) - fmaxf(x1, cA.x) + 1.0f;
        float ih = fminf(y2, cB.x) - fmaxf(y1, cA.y) + 1.0f;
        float il = fminf(z2, cB.y) - fmaxf(z1, cA.z) + 1.0f;
        iw = fmaxf(iw, 0.0f); ih = fmaxf(ih, 0.0f); il = fmaxf(il, 0.0f);
        float inter = iw * ih * il;
        float denom = v + cB.z - inter;     // same op order as reference
        bool over = ((double)inter >= BMID * (double)denom);  // exact
        int cidx = w * 64 + b2;
        if (cidx > row && over) word |= (1ull << b2);
    }
    mask[((size_t)bb * NW + w) * ROWS + row] = word;   // coalesced 512B/block
    if (w == g) {
        diagBand[((size_t)bb * ROWS + row) * 2 + 0] = word;
        if (g == NW - 1) diagBand[((size_t)bb * ROWS + row) * 2 + 1] = 0ull;
    }
    if (w == g + 1) diagBand[((size_t)bb * ROWS + row) * 2 + 1] = word;
}

// 6) pipelined greedy suppress (mask transposed: M[w][row])
__global__ void __launch_bounds__(1024) suppress_kernel(
        const unsigned long long* __restrict__ mask,
        const unsigned long long* __restrict__ diagBand,
        const float* __restrict__ sortedBox,
        float* __restrict__ out) {
    int bb = blockIdx.x;
    int tid = threadIdx.x;
    int lane = tid & 63;
    __shared__ unsigned long long remv[NW];
    __shared__ int kr[2][64];
    __shared__ int s_nk;
    for (int i = tid; i < NW; i += 1024) remv[i] = 0ull;
    if (tid == 0) {
        remv[NW - 1] = ~((1ull << (PRE_NMS - (NW - 1) * 64)) - 1ull);
        s_nk = 0;
    }
    __syncthreads();

    const unsigned long long* M = mask + (size_t)bb * NW * ROWS;
    const unsigned long long* D = diagBand + (size_t)bb * ROWS * 2;
    const float* sb = sortedBox + (size_t)bb * ROWS * 8;
    float* ob = out + (size_t)bb * POST_NMS * 7;

    int kept_total = 0, prev_nk = 0, prev_base = 0, cur = 0;
    unsigned long long diag0 = 0, band1 = 0, sup = 0;
    if (tid < 64) {
        diag0 = D[lane * 2 + 0];
        band1 = D[lane * 2 + 1];
    }

    for (int c = 0; c < NW; ++c) {
        unsigned long long nxt0 = 0, nxt1 = 0;
        if (tid < 64) {
            if (c + 1 < NW) {
                nxt0 = D[((c + 1) * 64 + lane) * 2 + 0];
                nxt1 = D[((c + 1) * 64 + lane) * 2 + 1];
            }
            unsigned long long alive = ~(remv[c] | sup);
            unsigned long long supn = 0;
            int nk = 0;
            while (alive && kept_total + nk < POST_NMS) {
                int b = __builtin_ctzll(alive);
                if (lane == 0) kr[cur][nk] = c * 64 + b;
                ++nk;
                alive &= ~(__shfl(diag0, b) | (1ull << b));
                supn |= __shfl(band1, b);
            }
            sup = supn;
            if (tid == 0) s_nk = nk;
        } else {
            int t = tid - 64;
            for (int w2 = c + 1 + t; w2 < NW; w2 += 960) {
                unsigned long long vv = remv[w2];
                for (int i = 0; i < prev_nk; ++i)
                    vv |= M[(size_t)w2 * ROWS + kr[cur ^ 1][i]];
                remv[w2] = vv;
            }
            for (int e = t; e < prev_nk * 7; e += 960) {
                int i = e / 7, j = e - i * 7;
                ob[(size_t)(prev_base + i) * 7 + j] =
                    sb[(size_t)kr[cur ^ 1][i] * 8 + (j == 0 ? 7 : j - 1)];
            }
        }
        __syncthreads();
        int nk = s_nk;
        prev_base = kept_total;
        kept_total += nk;
        prev_nk = nk;
        cur ^= 1;
        if (tid < 64) { diag0 = nxt0; band1 = nxt1; }
        if (kept_total >= POST_NMS) break;
    }
    for (int e = tid; e < prev_nk * 7; e += 1024) {
        int i = e / 7, j = e - i * 7;
        ob[(size_t)(prev_base + i) * 7 + j] =
            sb[(size_t)kr[cur ^ 1][i] * 8 + (j == 0 ? 7 : j - 1)];
    }
    for (int idx = kept_total * 7 + tid; idx < POST_NMS * 7; idx += 1024)
        ob[idx] = 0.0f;
}

extern "C" void kernel_launch(void* const* d_in, const int* in_sizes, int n_in,
                              void* d_out, int out_size, void* d_ws, size_t ws_size,
                              hipStream_t stream) {
    const float* scores_map = (const float*)d_in[0];
    const float* bbox_frame = (const float*)d_in[1];
    const float* im_info    = (const float*)d_in[2];
    const float* anchors    = (const float*)d_in[3];
    float* out = (float*)d_out;

    // workspace layout (bytes) — total 10,088,976 (same footprint)
    char* ws = (char*)d_ws;
    unsigned long long* mask     = (unsigned long long*)(ws + 0);          // 9,048,064
    unsigned int* binbase        = (unsigned int*)(ws + 0);                // aliases mask
    unsigned int* histR          = (unsigned int*)(ws + 524288);           // aliases mask: 4,194,304
    float* sortedBox             = (float*)(ws + 9048064);                 // 385,024
    unsigned long long* cand     = (unsigned long long*)(ws + 9433088);    // 131,072
    unsigned int* hist           = (unsigned int*)(ws + 9564160);          // 524,288 canonical
    unsigned long long* diagBand = (unsigned long long*)(ws + 9564160);    // aliases hist
    unsigned int* thr            = (unsigned int*)(ws + 10088448);         // 16
    unsigned int* partials       = (unsigned int*)(ws + 10088464);         // 512

    hipMemsetAsync(histR, 0, (size_t)NREP * B_ * NBIN * 4, stream);

    int total = B_ * N_;
    hist_kernel<<<(total + 255) / 256, 256, 0, stream>>>(scores_map, histR);
    partial_kernel<<<dim3(64, B_), 256, 0, stream>>>(histR, partials);
    rewrite_kernel<<<dim3(64, B_), 256, 0, stream>>>(histR, hist, binbase, partials, thr);
    compact_kernel<<<total / 256, 256, 0, stream>>>(scores_map, thr, cand, hist);
    bucket_decode<<<B_ * CAP / 256, 256, 0, stream>>>(cand, hist, binbase, thr,
                                                      bbox_frame, im_info, anchors,
                                                      sortedBox);
    mask_build<<<dim3(NW * NW, B_), 64, 0, stream>>>(sortedBox, mask, diagBand);
    suppress_kernel<<<B_, 1024, 0, stream>>>(mask, diagBand, sortedBox, out);
}